// Round 1
// baseline (291.452 us; speedup 1.0000x reference)
//
#include <hip/hip_runtime.h>
#include <hip/hip_bf16.h>

// Problem: N=8192 tokens, K=4096 quant dim, D=1024 out dim.
// out[n, d] = W[d, argmax_k x[n, k]]   (first-occurrence tie-break)
// Pure memory-bound: 128 MiB x-read + 16 MiB W-read (L3-resident) + 32 MiB out-write.

constexpr int N = 8192;
constexpr int K = 4096;
constexpr int D = 1024;
constexpr int BLOCK = 256; // 4 waves

__global__ __launch_bounds__(BLOCK) void steq_argmax_gather(
    const float* __restrict__ x,
    const float* __restrict__ W,
    float* __restrict__ out)
{
    const int n = blockIdx.x;
    const int t = threadIdx.x;

    // ---- Phase 1: argmax over x[n, :] (K=4096 floats = 1024 float4) ----
    const float4* xv = (const float4*)(x + (size_t)n * K);

    float best = -__builtin_inff();
    int bidx = K; // sentinel larger than any valid index

    // 4 coalesced float4 loads per thread: lane-contiguous 16B accesses.
    #pragma unroll
    for (int i = 0; i < K / (4 * BLOCK); ++i) {
        const int vec = i * BLOCK + t;
        const float4 v = xv[vec];
        const int base = vec * 4;
        // Increasing k within the thread: strict '>' keeps the first occurrence.
        if (v.x > best) { best = v.x; bidx = base + 0; }
        if (v.y > best) { best = v.y; bidx = base + 1; }
        if (v.z > best) { best = v.z; bidx = base + 2; }
        if (v.w > best) { best = v.w; bidx = base + 3; }
    }

    // Wave-level reduction (64 lanes). Prefer lower index on equal value.
    #pragma unroll
    for (int off = 32; off > 0; off >>= 1) {
        const float ov = __shfl_down(best, off, 64);
        const int   oi = __shfl_down(bidx, off, 64);
        if (ov > best || (ov == best && oi < bidx)) { best = ov; bidx = oi; }
    }

    // Cross-wave reduction via LDS (4 waves).
    __shared__ float s_val[BLOCK / 64];
    __shared__ int   s_idx[BLOCK / 64];
    const int wave = t >> 6;
    const int lane = t & 63;
    if (lane == 0) { s_val[wave] = best; s_idx[wave] = bidx; }
    __syncthreads();
    if (t == 0) {
        float bv = s_val[0];
        int   bi = s_idx[0];
        #pragma unroll
        for (int w = 1; w < BLOCK / 64; ++w) {
            if (s_val[w] > bv || (s_val[w] == bv && s_idx[w] < bi)) {
                bv = s_val[w]; bi = s_idx[w];
            }
        }
        s_idx[0] = bi;
    }
    __syncthreads();
    const int k = s_idx[0];

    // ---- Phase 2: out[n, :] = W[:, k]  (column gather, coalesced f4 store) ----
    // Each thread produces 4 consecutive d's -> one float4 store (16B/lane).
    // W reads are 16KB-strided (uncoalesced) but W = 16 MiB is L3-resident.
    const int d0 = t * 4;
    float4 o;
    o.x = W[(size_t)(d0 + 0) * K + k];
    o.y = W[(size_t)(d0 + 1) * K + k];
    o.z = W[(size_t)(d0 + 2) * K + k];
    o.w = W[(size_t)(d0 + 3) * K + k];
    ((float4*)(out + (size_t)n * D))[t] = o;
}

extern "C" void kernel_launch(void* const* d_in, const int* in_sizes, int n_in,
                              void* d_out, int out_size, void* d_ws, size_t ws_size,
                              hipStream_t stream) {
    const float* x = (const float*)d_in[0];
    const float* W = (const float*)d_in[1];
    float* out = (float*)d_out;
    steq_argmax_gather<<<N, BLOCK, 0, stream>>>(x, W, out);
}

// Round 2
// 213.389 us; speedup vs baseline: 1.3658x; 1.3658x over previous
//
#include <hip/hip_runtime.h>
#include <hip/hip_bf16.h>

// Problem: N=8192 tokens, K=4096 quant dim, D=1024 out dim.
// out[n, d] = W[d, argmax_k x[n, k]]   (first-occurrence tie-break)
//
// R1 lesson: gathering a column of row-major W (16 KiB stride) amplifies HBM
// fetch 16x (64B line per 4B float): FETCH_SIZE 465 MiB vs 144 MiB ideal.
// Fix: transpose W into d_ws once per call, gather becomes a contiguous
// 4 KiB coalesced row read.

constexpr int N = 8192;
constexpr int K = 4096;
constexpr int D = 1024;
constexpr int BLOCK = 256; // 4 waves

// ---------------- Transpose W (D x K, row-major) -> Wt (K x D) ----------------
constexpr int TILE = 64;

__global__ __launch_bounds__(256) void transpose_W(
    const float* __restrict__ W, float* __restrict__ Wt)
{
    // +1 padding: LDS reads in store phase hit banks 4*tx + r + j (mod 32)
    // -> only 2-way aliasing across the wave, which is free on gfx950 (m136).
    __shared__ float tile[TILE][TILE + 1];

    const int k0 = blockIdx.x * TILE; // K/64 = 64 tiles
    const int d0 = blockIdx.y * TILE; // D/64 = 16 tiles
    const int tx = threadIdx.x % 16;  // float4 column index within tile
    const int ty = threadIdx.x / 16;  // 16 rows per pass

    #pragma unroll
    for (int p = 0; p < 4; ++p) {
        const int r = p * 16 + ty; // d_local
        const float4 v = *(const float4*)(W + (size_t)(d0 + r) * K + k0 + tx * 4);
        tile[r][tx * 4 + 0] = v.x;
        tile[r][tx * 4 + 1] = v.y;
        tile[r][tx * 4 + 2] = v.z;
        tile[r][tx * 4 + 3] = v.w;
    }
    __syncthreads();
    #pragma unroll
    for (int p = 0; p < 4; ++p) {
        const int r = p * 16 + ty; // k_local
        float4 o;
        o.x = tile[tx * 4 + 0][r];
        o.y = tile[tx * 4 + 1][r];
        o.z = tile[tx * 4 + 2][r];
        o.w = tile[tx * 4 + 3][r];
        *(float4*)(Wt + (size_t)(k0 + r) * D + d0 + tx * 4) = o;
    }
}

// ---------------- argmax + row gather from Wt ----------------
__global__ __launch_bounds__(BLOCK) void steq_argmax_gather(
    const float* __restrict__ x,
    const float* __restrict__ Wt,
    float* __restrict__ out)
{
    const int n = blockIdx.x;
    const int t = threadIdx.x;

    // ---- Phase 1: argmax over x[n, :] (K=4096 floats = 1024 float4) ----
    const float4* xv = (const float4*)(x + (size_t)n * K);

    float best = -__builtin_inff();
    int bidx = K; // sentinel

    #pragma unroll
    for (int i = 0; i < K / (4 * BLOCK); ++i) {
        const int vec = i * BLOCK + t;
        const float4 v = xv[vec];
        const int base = vec * 4;
        if (v.x > best) { best = v.x; bidx = base + 0; }
        if (v.y > best) { best = v.y; bidx = base + 1; }
        if (v.z > best) { best = v.z; bidx = base + 2; }
        if (v.w > best) { best = v.w; bidx = base + 3; }
    }

    // Wave-level reduction (64 lanes), first-occurrence tie-break.
    #pragma unroll
    for (int off = 32; off > 0; off >>= 1) {
        const float ov = __shfl_down(best, off, 64);
        const int   oi = __shfl_down(bidx, off, 64);
        if (ov > best || (ov == best && oi < bidx)) { best = ov; bidx = oi; }
    }

    __shared__ float s_val[BLOCK / 64];
    __shared__ int   s_idx[BLOCK / 64];
    const int wave = t >> 6;
    const int lane = t & 63;
    if (lane == 0) { s_val[wave] = best; s_idx[wave] = bidx; }
    __syncthreads();
    if (t == 0) {
        float bv = s_val[0];
        int   bi = s_idx[0];
        #pragma unroll
        for (int w = 1; w < BLOCK / 64; ++w) {
            if (s_val[w] > bv || (s_val[w] == bv && s_idx[w] < bi)) {
                bv = s_val[w]; bi = s_idx[w];
            }
        }
        s_idx[0] = bi;
    }
    __syncthreads();
    const int k = s_idx[0];

    // ---- Phase 2: out[n, :] = Wt[k, :] — contiguous 4 KiB, coalesced f4 ----
    const float4 o = ((const float4*)(Wt + (size_t)k * D))[t];
    ((float4*)(out + (size_t)n * D))[t] = o;
}

extern "C" void kernel_launch(void* const* d_in, const int* in_sizes, int n_in,
                              void* d_out, int out_size, void* d_ws, size_t ws_size,
                              hipStream_t stream) {
    const float* x = (const float*)d_in[0];
    const float* W = (const float*)d_in[1];
    float* out = (float*)d_out;
    float* Wt  = (float*)d_ws; // K*D*4 = 16 MiB scratch

    dim3 tgrid(K / TILE, D / TILE); // (64, 16)
    transpose_W<<<tgrid, 256, 0, stream>>>(W, Wt);
    steq_argmax_gather<<<N, BLOCK, 0, stream>>>(x, Wt, out);
}

// Round 4
// 206.991 us; speedup vs baseline: 1.4080x; 1.0309x over previous
//
#include <hip/hip_runtime.h>
#include <hip/hip_bf16.h>

// Problem: N=8192 tokens, K=4096 quant dim, D=1024 out dim.
// out[n, d] = W[d, argmax_k x[n, k]]   (first-occurrence tie-break)
//
// R1: column gather of row-major W amplified HBM fetch 16x -> transpose W
//     into d_ws (R2), FETCH 465->~145 MiB.
// R4: batch the 4 independent x-loads explicitly (ILP) + nontemporal on the
//     x stream / out stream (keep Wt resident in L2). Nontemporal builtins
//     need clang ext_vector_type, not HIP_vector_type (R3 compile fail).

constexpr int N = 8192;
constexpr int K = 4096;
constexpr int D = 1024;
constexpr int BLOCK = 256; // 4 waves

typedef float vf4 __attribute__((ext_vector_type(4))); // clang-native float4

// ---------------- Transpose W (D x K, row-major) -> Wt (K x D) ----------------
constexpr int TILE = 64;

__global__ __launch_bounds__(256) void transpose_W(
    const float* __restrict__ W, float* __restrict__ Wt)
{
    __shared__ float tile[TILE][TILE + 1];

    const int k0 = blockIdx.x * TILE;
    const int d0 = blockIdx.y * TILE;
    const int tx = threadIdx.x % 16;
    const int ty = threadIdx.x / 16;

    #pragma unroll
    for (int p = 0; p < 4; ++p) {
        const int r = p * 16 + ty; // d_local
        const vf4 v = *(const vf4*)(W + (size_t)(d0 + r) * K + k0 + tx * 4);
        tile[r][tx * 4 + 0] = v.x;
        tile[r][tx * 4 + 1] = v.y;
        tile[r][tx * 4 + 2] = v.z;
        tile[r][tx * 4 + 3] = v.w;
    }
    __syncthreads();
    #pragma unroll
    for (int p = 0; p < 4; ++p) {
        const int r = p * 16 + ty; // k_local
        vf4 o;
        o.x = tile[tx * 4 + 0][r];
        o.y = tile[tx * 4 + 1][r];
        o.z = tile[tx * 4 + 2][r];
        o.w = tile[tx * 4 + 3][r];
        *(vf4*)(Wt + (size_t)(k0 + r) * D + d0 + tx * 4) = o;
    }
}

// ---------------- argmax + row gather from Wt ----------------
__global__ __launch_bounds__(BLOCK) void steq_argmax_gather(
    const float* __restrict__ x,
    const float* __restrict__ Wt,
    float* __restrict__ out)
{
    const int n = blockIdx.x;
    const int t = threadIdx.x;

    const vf4* xv = (const vf4*)(x + (size_t)n * K);

    // ---- Phase 1: issue all 4 independent 16B loads up front (ILP), ----
    // ---- nontemporal: x is streamed once, don't pollute L2.          ----
    vf4 v0 = __builtin_nontemporal_load(&xv[0 * BLOCK + t]);
    vf4 v1 = __builtin_nontemporal_load(&xv[1 * BLOCK + t]);
    vf4 v2 = __builtin_nontemporal_load(&xv[2 * BLOCK + t]);
    vf4 v3 = __builtin_nontemporal_load(&xv[3 * BLOCK + t]);

    float best = -__builtin_inff();
    int bidx = 0;
    // Increasing k order within the thread; strict '>' keeps first occurrence.
    #pragma unroll
    for (int i = 0; i < 4; ++i) {
        const vf4 v = (i == 0) ? v0 : (i == 1) ? v1 : (i == 2) ? v2 : v3;
        const int base = (i * BLOCK + t) * 4;
        if (v.x > best) { best = v.x; bidx = base + 0; }
        if (v.y > best) { best = v.y; bidx = base + 1; }
        if (v.z > best) { best = v.z; bidx = base + 2; }
        if (v.w > best) { best = v.w; bidx = base + 3; }
    }

    // Wave-level reduction (64 lanes), first-occurrence tie-break.
    #pragma unroll
    for (int off = 32; off > 0; off >>= 1) {
        const float ov = __shfl_down(best, off, 64);
        const int   oi = __shfl_down(bidx, off, 64);
        if (ov > best || (ov == best && oi < bidx)) { best = ov; bidx = oi; }
    }

    __shared__ float s_val[BLOCK / 64];
    __shared__ int   s_idx[BLOCK / 64];
    const int wave = t >> 6;
    const int lane = t & 63;
    if (lane == 0) { s_val[wave] = best; s_idx[wave] = bidx; }
    __syncthreads();
    if (t == 0) {
        float bv = s_val[0];
        int   bi = s_idx[0];
        #pragma unroll
        for (int w = 1; w < BLOCK / 64; ++w) {
            if (s_val[w] > bv || (s_val[w] == bv && s_idx[w] < bi)) {
                bv = s_val[w]; bi = s_idx[w];
            }
        }
        s_idx[0] = bi;
    }
    __syncthreads();
    const int k = s_idx[0];

    // ---- Phase 2: out[n, :] = Wt[k, :] — contiguous 4 KiB, coalesced f4 ----
    const vf4 o = ((const vf4*)(Wt + (size_t)k * D))[t];
    __builtin_nontemporal_store(o, &((vf4*)(out + (size_t)n * D))[t]);
}

extern "C" void kernel_launch(void* const* d_in, const int* in_sizes, int n_in,
                              void* d_out, int out_size, void* d_ws, size_t ws_size,
                              hipStream_t stream) {
    const float* x = (const float*)d_in[0];
    const float* W = (const float*)d_in[1];
    float* out = (float*)d_out;
    float* Wt  = (float*)d_ws; // K*D*4 = 16 MiB scratch

    dim3 tgrid(K / TILE, D / TILE); // (64, 16)
    transpose_W<<<tgrid, 256, 0, stream>>>(W, Wt);
    steq_argmax_gather<<<N, BLOCK, 0, stream>>>(x, Wt, out);
}